// Round 5
// baseline (238.400 us; speedup 1.0000x reference)
//
#include <hip/hip_runtime.h>

// GNNEncoder fused MFMA kernel (round 7: LDS-free loop, compiler-pack bf16).
// B=16, S=2048, N=64, HD=32.
// Round-5/6 post-mortem (both absmax=inf): the only inf-capable mechanism
// is the v_cvt_pk_bf16_f32 inline asm delivering non-bf16 payload (garbage
// bf16 exponents ~1e38 -> f32 MFMA accumulator overflow). Routing was
// triple-derived from the validated C-layout and is finite-wrong-safe.
// Fix: replace the asm with (__bf16) casts + bit_cast + shift-or packing
// (definitionally correct; compiler emits cvt_pk itself — guide m240).
// Everything else unchanged from round 6:
//  - GEMM2 transposed (h2^T = W2 @ cat^T); phase-1 C-layout -> B-fragments
//    via 8 packs + 8 shfl_xor(32) + cndmask selects (T12 structure):
//      B2 = {lh?p2:d0, lh?p3:d1, lh?d2:p0, lh?d3:p1}
//      B3 = {lh?p6:d4, lh?p7:d5, lh?d6:p4, lh?d7:p5}
//  - no catg LDS, no in-loop barriers; per-lane adj rowsums + shfl_xor;
//    red[f][i] transposed reduce; staggered nt pipeline.
#define BN 16
#define SN 2048
#define NV 64
#define HD 32
#define SCHUNK 32           // s per block (1024 blocks)
#define NSUB 8              // iters; 1 s-row per wave per iter

typedef short  bf8_t  __attribute__((ext_vector_type(8)));   // raw-bit MFMA view
typedef __bf16 bfv8   __attribute__((ext_vector_type(8)));
typedef float  f32x16 __attribute__((ext_vector_type(16)));
typedef int    i32x4  __attribute__((ext_vector_type(4)));

#define MFMA32(a, b, c) __builtin_amdgcn_mfma_f32_32x32x16_bf16( \
    __builtin_bit_cast(bf8_t, (a)), __builtin_bit_cast(bf8_t, (b)), (c), 0, 0, 0)

// Pack two f32 -> one dword of 2x bf16 (lo in [15:0], hi in [31:16]).
// Pure compiler casts: correct by construction (no inline asm).
static __device__ __forceinline__ int pack2bf(float lo, float hi) {
    const unsigned short a = __builtin_bit_cast(unsigned short, (__bf16)lo);
    const unsigned short b = __builtin_bit_cast(unsigned short, (__bf16)hi);
    return (int)a | ((int)b << 16);
}

// C-layout f32x16 (col i=l31, rows f=(r&3)+8*(r>>2)+4*lh) -> B-fragments of
// cat^T for k=32..47 (B2) and k=48..63 (B3). d[q] packs f-pair (4lh+.. see
// derivation) of this half's rows; p[q] = partner half-wave's d[q].
static __device__ __forceinline__ void make_bagg(
    const f32x16& c, const int lh, i32x4& B2, i32x4& B3)
{
    int d[8], p[8];
    #pragma unroll
    for (int q = 0; q < 8; ++q) d[q] = pack2bf(c[2 * q], c[2 * q + 1]);
    #pragma unroll
    for (int q = 0; q < 8; ++q) p[q] = __shfl_xor(d[q], 32);
    B2 = (i32x4){ lh ? p[2] : d[0], lh ? p[3] : d[1],
                  lh ? d[2] : p[0], lh ? d[3] : p[1] };
    B3 = (i32x4){ lh ? p[6] : d[4], lh ? p[7] : d[5],
                  lh ? d[6] : p[4], lh ? d[7] : p[5] };
}

__global__ __launch_bounds__(256, 3) void gnn_mfma(
    const float* __restrict__ x,    // [B,S,N]
    const float* __restrict__ adj,  // [N,N]
    const float* __restrict__ w1,   // [HD]
    const float* __restrict__ b1,   // [HD]
    const float* __restrict__ w2,   // [HD, 2*HD]
    const float* __restrict__ b2,   // [HD]
    float* __restrict__ out)        // [B, N*HD]
{
    __shared__ float red[HD * NV];          // red[f][i], 8 KB — only LDS left

    const int tid  = threadIdx.x;
    const int w    = tid >> 6;
    const int lane = tid & 63;
    const int l31  = lane & 31;
    const int lh   = lane >> 5;             // 0/1 half-wave
    const int b    = blockIdx.x >> 6;       // 64 chunks per batch row
    const int chk  = blockIdx.x & 63;
    const int sbase = chk * SCHUNK;

    // zero the block reduce buffer (ordered before epilogue atomics by the
    // pre-epilogue __syncthreads below)
    #pragma unroll
    for (int q = 0; q < (NV * HD) / 256; ++q) red[tid + q * 256] = 0.f;

    // --- An B-fragments (GEMM1): per-lane row-sums from the same loads ---
    // B[k=j][n=i]: lane -> n = nt*32+l31, k = kk*16 + lh*8 + e
    bfv8 an[2][4];
    #pragma unroll
    for (int nt = 0; nt < 2; ++nt) {
        const int i = nt * 32 + l31;
        float av[4][8];
        float psum = 0.f;
        #pragma unroll
        for (int kk = 0; kk < 4; ++kk) {
            const int j0 = kk * 16 + lh * 8;
            const float4 a0 = *(const float4*)(adj + i * NV + j0);
            const float4 a1 = *(const float4*)(adj + i * NV + j0 + 4);
            av[kk][0] = a0.x; av[kk][1] = a0.y; av[kk][2] = a0.z; av[kk][3] = a0.w;
            av[kk][4] = a1.x; av[kk][5] = a1.y; av[kk][6] = a1.z; av[kk][7] = a1.w;
            psum += a0.x + a0.y + a0.z + a0.w + a1.x + a1.y + a1.z + a1.w;
        }
        const float fullsum = psum + __shfl_xor(psum, 32);  // partner half-row
        const float rsi = 1.f / (fullsum + 1e-8f);
        #pragma unroll
        for (int kk = 0; kk < 4; ++kk) {
            bfv8 v;
            #pragma unroll
            for (int e = 0; e < 8; ++e) v[e] = (__bf16)(av[kk][e] * rsi);
            an[nt][kk] = v;
        }
    }

    // --- W2 A-fragments (GEMM2 transposed): A[m=f'][k]: m=l31, k=kk*16+lh*8+e ---
    bfv8 wf[4];
    #pragma unroll
    for (int kk = 0; kk < 4; ++kk) {
        const int k0 = kk * 16 + lh * 8;
        const float4 a0 = *(const float4*)(w2 + l31 * (2 * HD) + k0);
        const float4 a1 = *(const float4*)(w2 + l31 * (2 * HD) + k0 + 4);
        bfv8 v;
        v[0] = (__bf16)a0.x; v[1] = (__bf16)a0.y; v[2] = (__bf16)a0.z; v[3] = (__bf16)a0.w;
        v[4] = (__bf16)a1.x; v[5] = (__bf16)a1.y; v[6] = (__bf16)a1.z; v[7] = (__bf16)a1.w;
        wf[kk] = v;
    }

    // per-lane fc1 constants
    const float w1f = w1[l31];
    const float b1f = b1[l31];
    float w1k[2][8], b1k[2][8];
    #pragma unroll
    for (int kk = 0; kk < 2; ++kk) {
        const int k0 = kk * 16 + lh * 8;
        #pragma unroll
        for (int e = 0; e < 8; ++e) { w1k[kk][e] = w1[k0 + e]; b1k[kk][e] = b1[k0 + e]; }
    }
    // fc2 bias in the h2^T C-layout: b2[f'] with f' = (r&3)+8*(r>>2)+4*lh
    float b2r[16];
    #pragma unroll
    for (int r = 0; r < 16; ++r) b2r[r] = b2[(r & 3) + 8 * (r >> 2) + 4 * lh];

    f32x16 macc0, macc1;   // mean accumulators: i = l31 / 32+l31, f' in regs
    #pragma unroll
    for (int r = 0; r < 16; ++r) { macc0[r] = 0.f; macc1[r] = 0.f; }

    for (int t = 0; t < NSUB; ++t) {
        const float* xp = x + ((size_t)b * SN + sbase + t * 4 + w) * (size_t)NV;

        // ---- fc1 A-fragments for GEMM1 (direct broadcast loads) ----
        bfv8 a1f[4];
        #pragma unroll
        for (int kk = 0; kk < 4; ++kk) {
            const int j0 = kk * 16 + lh * 8;
            const float4 xa = *(const float4*)(xp + j0);
            const float4 xb = *(const float4*)(xp + j0 + 4);
            bfv8 v;
            v[0] = (__bf16)fmaxf(xa.x * w1f + b1f, 0.f);
            v[1] = (__bf16)fmaxf(xa.y * w1f + b1f, 0.f);
            v[2] = (__bf16)fmaxf(xa.z * w1f + b1f, 0.f);
            v[3] = (__bf16)fmaxf(xa.w * w1f + b1f, 0.f);
            v[4] = (__bf16)fmaxf(xb.x * w1f + b1f, 0.f);
            v[5] = (__bf16)fmaxf(xb.y * w1f + b1f, 0.f);
            v[6] = (__bf16)fmaxf(xb.z * w1f + b1f, 0.f);
            v[7] = (__bf16)fmaxf(xb.w * w1f + b1f, 0.f);
            a1f[kk] = v;
        }
        const float xv0 = xp[l31];
        const float xv1 = xp[32 + l31];

        // ---- staggered per-nt pipeline: GEMM1 -> pack/exchange -> GEMM2 ----
        #pragma unroll
        for (int nt = 0; nt < 2; ++nt) {
            // Phase 1: aggT[f][i] = sum_j hT[f][j] * An[i][j]
            f32x16 c1;
            #pragma unroll
            for (int r = 0; r < 16; ++r) c1[r] = 0.f;
            #pragma unroll
            for (int kk = 0; kk < 4; ++kk) c1 = MFMA32(a1f[kk], an[nt][kk], c1);

            // in-register transpose: C-layout -> cat^T B-fragments (k=32..63)
            i32x4 B2, B3;
            make_bagg(c1, lh, B2, B3);

            // Phase 2: h2^T = relu(W2 @ cat^T + b2); A=wf, B=(h | agg)
            const float xv = (nt == 0) ? xv0 : xv1;
            f32x16 c;
            #pragma unroll
            for (int r = 0; r < 16; ++r) c[r] = 0.f;
            #pragma unroll
            for (int kk = 0; kk < 2; ++kk) {   // h part: B[k=f][n=i] = h[i][f]
                bfv8 v;
                #pragma unroll
                for (int e = 0; e < 8; ++e)
                    v[e] = (__bf16)fmaxf(xv * w1k[kk][e] + b1k[kk][e], 0.f);
                c = MFMA32(wf[kk], v, c);
            }
            c = MFMA32(wf[2], B2, c);          // agg part k=32..47
            c = MFMA32(wf[3], B3, c);          // agg part k=48..63
            #pragma unroll
            for (int r = 0; r < 16; ++r) {
                const float h2 = fmaxf(c[r] + b2r[r], 0.f);
                if (nt == 0) macc0[r] += h2; else macc1[r] += h2;
            }
        }
    }

    // ---- epilogue: cross-wave reduce in LDS (red[f][i]: conflict-free) ----
    __syncthreads();   // all red[] zeroing precedes any atomicAdd below
    #pragma unroll
    for (int r = 0; r < 16; ++r) {
        const int fr = (r & 3) + 8 * (r >> 2) + 4 * lh;   // f'
        atomicAdd(&red[fr * NV + l31],      macc0[r]);
        atomicAdd(&red[fr * NV + 32 + l31], macc1[r]);
    }
    __syncthreads();
    const float inv = 1.f / (float)SN;
    #pragma unroll
    for (int q = 0; q < (NV * HD) / 256; ++q) {
        const int e = tid + q * 256;       // e = f*64 + i (linear, conflict-free)
        const int i = e & 63, f = e >> 6;
        atomicAdd(out + (size_t)b * (NV * HD) + i * HD + f, red[e] * inv);
    }
}

extern "C" void kernel_launch(void* const* d_in, const int* in_sizes, int n_in,
                              void* d_out, int out_size, void* d_ws, size_t ws_size,
                              hipStream_t stream) {
    const float* x   = (const float*)d_in[0];
    const float* adj = (const float*)d_in[1];
    const float* w1  = (const float*)d_in[2];
    const float* b1  = (const float*)d_in[3];
    const float* w2  = (const float*)d_in[4];
    const float* b2  = (const float*)d_in[5];
    float* out = (float*)d_out;

    hipMemsetAsync(out, 0, (size_t)out_size * sizeof(float), stream);
    gnn_mfma<<<dim3(BN * 64), dim3(256), 0, stream>>>(x, adj, w1, b1, w2, b2, out);
}

// Round 6
// 158.770 us; speedup vs baseline: 1.5015x; 1.5015x over previous
//
#include <hip/hip_runtime.h>

// GNNEncoder fused MFMA kernel (round 8: round-2 structure + proven fixes).
// B=16, S=2048, N=64, HD=32.
// Round-7 post-mortem: the in-register-transpose (LDS-free) path spills
// (~165 live regs), WRITE_SIZE 84 MB of scratch, 178 µs. Abandoned.
// This kernel = round-2 (best, 60 µs) with each measured defect fixed:
//  - occupancy was GRID-capped (512 blocks = 2/CU = 25% ceiling):
//    SCHUNK 64->32 => 1024 blocks; union catg/red => LDS 36.9 KB => 4
//    blocks/CU resident (16 waves/CU, 50% ceiling).
//  - 16 in-loop barriers + xs staging deleted (x rows and catg slices are
//    wave-private; direct global broadcast loads — validated round 4).
//  - CATP 40->36: 0 bank conflicts (measured round 4), reads as 2x bfv4.
//  - prologue: per-lane adj rowsums + shfl_xor(32), no rs LDS (validated
//    round 7).
//  - TCH=8 kept: 2 s-rows/wave/iter => 4 independent MFMA chains per phase
//    (round 4's ILP loss was the regression cause).
#define BN 16
#define SN 2048
#define NV 64
#define HD 32
#define TCH 8               // s-rows per iteration (2 per wave)
#define SCHUNK 32           // s per block (1024 blocks)
#define NSUB (SCHUNK / TCH) // 4
#define CATP 36             // padded f-dim of catg (72 B rows, 0-conflict)

typedef short  bf8_t  __attribute__((ext_vector_type(8)));   // raw-bit MFMA view
typedef __bf16 bfv8   __attribute__((ext_vector_type(8)));
typedef __bf16 bfv4   __attribute__((ext_vector_type(4)));
typedef float  f32x16 __attribute__((ext_vector_type(16)));

#define MFMA32(a, b, c) __builtin_amdgcn_mfma_f32_32x32x16_bf16( \
    __builtin_bit_cast(bf8_t, (a)), __builtin_bit_cast(bf8_t, (b)), (c), 0, 0, 0)

__global__ __launch_bounds__(256, 3) void gnn_mfma(
    const float* __restrict__ x,    // [B,S,N]
    const float* __restrict__ adj,  // [N,N]
    const float* __restrict__ w1,   // [HD]
    const float* __restrict__ b1,   // [HD]
    const float* __restrict__ w2,   // [HD, 2*HD]
    const float* __restrict__ b2,   // [HD]
    float* __restrict__ out)        // [B, N*HD]
{
    // catg (loop) and red (epilogue) never live simultaneously; the barrier
    // before red-zeroing orders all catg accesses first. 36864 B total.
    __shared__ union SMem {
        __bf16 catg[TCH][NV][CATP];   // 36864 B
        float  red[NV * HD];          //  8192 B
    } sm;

    const int tid  = threadIdx.x;
    const int w    = tid >> 6;
    const int lane = tid & 63;
    const int l31  = lane & 31;
    const int lh   = lane >> 5;             // 0/1 half-wave
    const int b    = blockIdx.x >> 6;       // 64 chunks per batch row
    const int chk  = blockIdx.x & 63;
    const int sbase = chk * SCHUNK;

    // --- An B-fragments (GEMM1): per-lane row-sums from the same loads ---
    // B[k=j][n=i]: lane -> n = nt*32+l31, k = kk*16 + lh*8 + e
    bfv8 an[2][4];
    #pragma unroll
    for (int nt = 0; nt < 2; ++nt) {
        const int i = nt * 32 + l31;
        float av[4][8];
        float psum = 0.f;
        #pragma unroll
        for (int kk = 0; kk < 4; ++kk) {
            const int j0 = kk * 16 + lh * 8;
            const float4 a0 = *(const float4*)(adj + i * NV + j0);
            const float4 a1 = *(const float4*)(adj + i * NV + j0 + 4);
            av[kk][0] = a0.x; av[kk][1] = a0.y; av[kk][2] = a0.z; av[kk][3] = a0.w;
            av[kk][4] = a1.x; av[kk][5] = a1.y; av[kk][6] = a1.z; av[kk][7] = a1.w;
            psum += a0.x + a0.y + a0.z + a0.w + a1.x + a1.y + a1.z + a1.w;
        }
        const float fullsum = psum + __shfl_xor(psum, 32);  // partner half-row
        const float rsi = 1.f / (fullsum + 1e-8f);
        #pragma unroll
        for (int kk = 0; kk < 4; ++kk) {
            bfv8 v;
            #pragma unroll
            for (int e = 0; e < 8; ++e) v[e] = (__bf16)(av[kk][e] * rsi);
            an[nt][kk] = v;
        }
    }

    // --- W2^T B-fragments (GEMM2): B[k][n=f']: f' = l31, k = kk*16+lh*8+e ---
    bfv8 wf[4];
    #pragma unroll
    for (int kk = 0; kk < 4; ++kk) {
        const int k0 = kk * 16 + lh * 8;
        const float4 a0 = *(const float4*)(w2 + l31 * (2 * HD) + k0);
        const float4 a1 = *(const float4*)(w2 + l31 * (2 * HD) + k0 + 4);
        bfv8 v;
        v[0] = (__bf16)a0.x; v[1] = (__bf16)a0.y; v[2] = (__bf16)a0.z; v[3] = (__bf16)a0.w;
        v[4] = (__bf16)a1.x; v[5] = (__bf16)a1.y; v[6] = (__bf16)a1.z; v[7] = (__bf16)a1.w;
        wf[kk] = v;
    }

    // per-lane fc1/fc2 constants
    const float w1f = w1[l31];
    const float b1f = b1[l31];
    const float b2f = b2[l31];
    float w1k[2][8], b1k[2][8];
    #pragma unroll
    for (int kk = 0; kk < 2; ++kk) {
        const int k0 = kk * 16 + lh * 8;
        #pragma unroll
        for (int e = 0; e < 8; ++e) { w1k[kk][e] = w1[k0 + e]; b1k[kk][e] = b1[k0 + e]; }
    }

    f32x16 macc0, macc1;   // mean accumulators, ihalf = 0 / 1
    #pragma unroll
    for (int r = 0; r < 16; ++r) { macc0[r] = 0.f; macc1[r] = 0.f; }

    for (int t = 0; t < NSUB; ++t) {
        // this wave's two s-rows for this iteration (wave-private; no barriers)
        const float* xp0 = x + ((size_t)b * SN + sbase + t * TCH + 2 * w) * (size_t)NV;
        const float* xp1 = xp0 + NV;

        // ---- Phase 1: GEMM1 -> aggT, written to catg (wave-private slices) ----
        #pragma unroll
        for (int sp = 0; sp < 2; ++sp) {
            const float* xp = sp ? xp1 : xp0;
            const int sl = 2 * w + sp;
            bfv8 a1f[4];
            #pragma unroll
            for (int kk = 0; kk < 4; ++kk) {
                const int j0 = kk * 16 + lh * 8;
                const float4 xa = *(const float4*)(xp + j0);
                const float4 xb = *(const float4*)(xp + j0 + 4);
                bfv8 v;
                v[0] = (__bf16)fmaxf(xa.x * w1f + b1f, 0.f);
                v[1] = (__bf16)fmaxf(xa.y * w1f + b1f, 0.f);
                v[2] = (__bf16)fmaxf(xa.z * w1f + b1f, 0.f);
                v[3] = (__bf16)fmaxf(xa.w * w1f + b1f, 0.f);
                v[4] = (__bf16)fmaxf(xb.x * w1f + b1f, 0.f);
                v[5] = (__bf16)fmaxf(xb.y * w1f + b1f, 0.f);
                v[6] = (__bf16)fmaxf(xb.z * w1f + b1f, 0.f);
                v[7] = (__bf16)fmaxf(xb.w * w1f + b1f, 0.f);
                a1f[kk] = v;
            }
            #pragma unroll
            for (int nt = 0; nt < 2; ++nt) {
                f32x16 c;
                #pragma unroll
                for (int r = 0; r < 16; ++r) c[r] = 0.f;
                #pragma unroll
                for (int kk = 0; kk < 4; ++kk) c = MFMA32(a1f[kk], an[nt][kk], c);
                // C[m=f][n=i]: col=l31 -> i, row=(reg&3)+8*(reg>>2)+4*lh -> f
                const int i = nt * 32 + l31;
                #pragma unroll
                for (int g = 0; g < 4; ++g) {
                    const int f0 = g * 8 + 4 * lh;
                    bfv4 pv;
                    pv[0] = (__bf16)c[g * 4 + 0]; pv[1] = (__bf16)c[g * 4 + 1];
                    pv[2] = (__bf16)c[g * 4 + 2]; pv[3] = (__bf16)c[g * 4 + 3];
                    *(bfv4*)&sm.catg[sl][i][f0] = pv;
                }
            }
        }

        // ---- Phase 2: GEMM2 (same-wave catg slices; compiler orders ds ops) ----
        #pragma unroll
        for (int p = 0; p < 4; ++p) {
            const int sp = p >> 1;
            const int sl = 2 * w + sp;
            const int ih = p & 1;
            const int i  = ih * 32 + l31;
            const float xv = (sp ? xp1 : xp0)[i];
            f32x16 c;
            #pragma unroll
            for (int r = 0; r < 16; ++r) c[r] = 0.f;
            #pragma unroll
            for (int kk = 0; kk < 2; ++kk) {   // h part, k in [0,32)
                bfv8 v;
                #pragma unroll
                for (int e = 0; e < 8; ++e)
                    v[e] = (__bf16)fmaxf(xv * w1k[kk][e] + b1k[kk][e], 0.f);
                c = MFMA32(v, wf[kk], c);
            }
            #pragma unroll
            for (int kk = 2; kk < 4; ++kk) {   // agg part, k in [32,64)
                const int f0 = (kk - 2) * 16 + lh * 8;
                const bfv4 lo = *(const bfv4*)&sm.catg[sl][i][f0];
                const bfv4 hi = *(const bfv4*)&sm.catg[sl][i][f0 + 4];
                bfv8 v;
                #pragma unroll
                for (int e = 0; e < 4; ++e) { v[e] = lo[e]; v[e + 4] = hi[e]; }
                c = MFMA32(v, wf[kk], c);
            }
            #pragma unroll
            for (int r = 0; r < 16; ++r) {
                const float h2 = fmaxf(c[r] + b2f, 0.f);
                if (ih == 0) macc0[r] += h2; else macc1[r] += h2;
            }
        }
    }

    // ---- epilogue: cross-wave reduce in LDS (red aliases catg), atomics ----
    __syncthreads();   // all catg reads complete before red overwrites it
    #pragma unroll
    for (int q = 0; q < (NV * HD) / 256; ++q) sm.red[tid + q * 256] = 0.f;
    __syncthreads();   // zeroing visible to all waves
    #pragma unroll
    for (int r = 0; r < 16; ++r) {
        const int row = (r & 3) + 8 * (r >> 2) + 4 * lh;  // i within half
        atomicAdd(&sm.red[row * HD + l31], macc0[r]);
        atomicAdd(&sm.red[(row + 32) * HD + l31], macc1[r]);
    }
    __syncthreads();
    const float inv = 1.f / (float)SN;
    #pragma unroll
    for (int q = 0; q < (NV * HD) / 256; ++q) {
        const int e = tid + q * 256;       // e = i*HD + f
        atomicAdd(out + (size_t)b * (NV * HD) + e, sm.red[e] * inv);
    }
}

extern "C" void kernel_launch(void* const* d_in, const int* in_sizes, int n_in,
                              void* d_out, int out_size, void* d_ws, size_t ws_size,
                              hipStream_t stream) {
    const float* x   = (const float*)d_in[0];
    const float* adj = (const float*)d_in[1];
    const float* w1  = (const float*)d_in[2];
    const float* b1  = (const float*)d_in[3];
    const float* w2  = (const float*)d_in[4];
    const float* b2  = (const float*)d_in[5];
    float* out = (float*)d_out;

    hipMemsetAsync(out, 0, (size_t)out_size * sizeof(float), stream);
    gnn_mfma<<<dim3(BN * 64), dim3(256), 0, stream>>>(x, adj, w1, b1, w2, b2, out);
}

// Round 7
// 127.642 us; speedup vs baseline: 1.8677x; 1.2439x over previous
//
#include <hip/hip_runtime.h>

// GNNEncoder fused MFMA kernel (round 9: round-2 geometry, barrier-free).
// B=16, S=2048, N=64, HD=32.
// Round-8 post-mortem: launch_bounds>=3 is the recurring poison (VGPR 84,
// +14 MB scratch-class WRITE traffic, occupancy flat) — this kernel's live
// set needs the (256,2) budget. 1024-block grids lost twice even when
// clean (r4: 87 us): prologue/epilogue fixed costs dominate the occupancy
// gain. So: ONE-axis change from the 60-us round-2 champion:
//  - xs staging + all 16 in-loop barriers deleted (x rows and catg slices
//    are wave-private — correctness proven in r4/r7/r8). Waves run free;
//    no block-wide vmcnt drains.
//  - per-lane adj rowsums + shfl_xor(32) (validated r7/r8): rs LDS and its
//    barrier gone.
//  - CATP 40->36 (validated r4/r8): kills the 1M conflict cycles.
// Geometry unchanged from round 2: SCHUNK=64, TCH=8 (2 s-rows/wave/iter,
// 4 independent MFMA chains per phase), 512 blocks, launch_bounds(256,2).
#define BN 16
#define SN 2048
#define NV 64
#define HD 32
#define TCH 8               // s-rows per iteration (2 per wave)
#define SCHUNK 64           // s per block (512 blocks)
#define NSUB (SCHUNK / TCH) // 8
#define CATP 36             // padded f-dim of catg (72 B rows)

typedef short  bf8_t  __attribute__((ext_vector_type(8)));   // raw-bit MFMA view
typedef __bf16 bfv8   __attribute__((ext_vector_type(8)));
typedef __bf16 bfv4   __attribute__((ext_vector_type(4)));
typedef float  f32x16 __attribute__((ext_vector_type(16)));

#define MFMA32(a, b, c) __builtin_amdgcn_mfma_f32_32x32x16_bf16( \
    __builtin_bit_cast(bf8_t, (a)), __builtin_bit_cast(bf8_t, (b)), (c), 0, 0, 0)

__global__ __launch_bounds__(256, 2) void gnn_mfma(
    const float* __restrict__ x,    // [B,S,N]
    const float* __restrict__ adj,  // [N,N]
    const float* __restrict__ w1,   // [HD]
    const float* __restrict__ b1,   // [HD]
    const float* __restrict__ w2,   // [HD, 2*HD]
    const float* __restrict__ b2,   // [HD]
    float* __restrict__ out)        // [B, N*HD]
{
    __shared__ __bf16 catg[TCH][NV][CATP];  // 36864 B, wave-private s slices
    __shared__ float  red[NV * HD];         //  8192 B

    const int tid  = threadIdx.x;
    const int w    = tid >> 6;
    const int lane = tid & 63;
    const int l31  = lane & 31;
    const int lh   = lane >> 5;             // 0/1 half-wave
    const int b    = blockIdx.x >> 5;       // 32 chunks per batch row
    const int chk  = blockIdx.x & 31;
    const int sbase = chk * SCHUNK;

    // zero the block reduce buffer (ordered before epilogue atomics by the
    // pre-atomics __syncthreads below)
    #pragma unroll
    for (int q = 0; q < (NV * HD) / 256; ++q) red[tid + q * 256] = 0.f;

    // --- An B-fragments (GEMM1): per-lane row-sums from the same loads ---
    // B[k=j][n=i]: lane -> n = nt*32+l31, k = kk*16 + lh*8 + e
    bfv8 an[2][4];
    #pragma unroll
    for (int nt = 0; nt < 2; ++nt) {
        const int i = nt * 32 + l31;
        float av[4][8];
        float psum = 0.f;
        #pragma unroll
        for (int kk = 0; kk < 4; ++kk) {
            const int j0 = kk * 16 + lh * 8;
            const float4 a0 = *(const float4*)(adj + i * NV + j0);
            const float4 a1 = *(const float4*)(adj + i * NV + j0 + 4);
            av[kk][0] = a0.x; av[kk][1] = a0.y; av[kk][2] = a0.z; av[kk][3] = a0.w;
            av[kk][4] = a1.x; av[kk][5] = a1.y; av[kk][6] = a1.z; av[kk][7] = a1.w;
            psum += a0.x + a0.y + a0.z + a0.w + a1.x + a1.y + a1.z + a1.w;
        }
        const float fullsum = psum + __shfl_xor(psum, 32);  // partner half-row
        const float rsi = 1.f / (fullsum + 1e-8f);
        #pragma unroll
        for (int kk = 0; kk < 4; ++kk) {
            bfv8 v;
            #pragma unroll
            for (int e = 0; e < 8; ++e) v[e] = (__bf16)(av[kk][e] * rsi);
            an[nt][kk] = v;
        }
    }

    // --- W2^T B-fragments (GEMM2): B[k][n=f']: f' = l31, k = kk*16+lh*8+e ---
    bfv8 wf[4];
    #pragma unroll
    for (int kk = 0; kk < 4; ++kk) {
        const int k0 = kk * 16 + lh * 8;
        const float4 a0 = *(const float4*)(w2 + l31 * (2 * HD) + k0);
        const float4 a1 = *(const float4*)(w2 + l31 * (2 * HD) + k0 + 4);
        bfv8 v;
        v[0] = (__bf16)a0.x; v[1] = (__bf16)a0.y; v[2] = (__bf16)a0.z; v[3] = (__bf16)a0.w;
        v[4] = (__bf16)a1.x; v[5] = (__bf16)a1.y; v[6] = (__bf16)a1.z; v[7] = (__bf16)a1.w;
        wf[kk] = v;
    }

    // per-lane fc1/fc2 constants
    const float w1f = w1[l31];
    const float b1f = b1[l31];
    const float b2f = b2[l31];
    float w1k[2][8], b1k[2][8];
    #pragma unroll
    for (int kk = 0; kk < 2; ++kk) {
        const int k0 = kk * 16 + lh * 8;
        #pragma unroll
        for (int e = 0; e < 8; ++e) { w1k[kk][e] = w1[k0 + e]; b1k[kk][e] = b1[k0 + e]; }
    }

    f32x16 macc0, macc1;   // mean accumulators, ihalf = 0 / 1
    #pragma unroll
    for (int r = 0; r < 16; ++r) { macc0[r] = 0.f; macc1[r] = 0.f; }

    for (int t = 0; t < NSUB; ++t) {
        // this wave's two s-rows for this iteration (wave-private; no barriers)
        const float* xp0 = x + ((size_t)b * SN + sbase + t * TCH + 2 * w) * (size_t)NV;
        const float* xp1 = xp0 + NV;

        // phase-2 scalars issued early so their latency hides under phase 1
        const float xv00 = xp0[l31];
        const float xv01 = xp0[32 + l31];
        const float xv10 = xp1[l31];
        const float xv11 = xp1[32 + l31];

        // ---- Phase 1: GEMM1 -> aggT, written to catg (wave-private slices) ----
        #pragma unroll
        for (int sp = 0; sp < 2; ++sp) {
            const float* xp = sp ? xp1 : xp0;
            const int sl = 2 * w + sp;
            bfv8 a1f[4];
            #pragma unroll
            for (int kk = 0; kk < 4; ++kk) {
                const int j0 = kk * 16 + lh * 8;
                const float4 xa = *(const float4*)(xp + j0);
                const float4 xb = *(const float4*)(xp + j0 + 4);
                bfv8 v;
                v[0] = (__bf16)fmaxf(xa.x * w1f + b1f, 0.f);
                v[1] = (__bf16)fmaxf(xa.y * w1f + b1f, 0.f);
                v[2] = (__bf16)fmaxf(xa.z * w1f + b1f, 0.f);
                v[3] = (__bf16)fmaxf(xa.w * w1f + b1f, 0.f);
                v[4] = (__bf16)fmaxf(xb.x * w1f + b1f, 0.f);
                v[5] = (__bf16)fmaxf(xb.y * w1f + b1f, 0.f);
                v[6] = (__bf16)fmaxf(xb.z * w1f + b1f, 0.f);
                v[7] = (__bf16)fmaxf(xb.w * w1f + b1f, 0.f);
                a1f[kk] = v;
            }
            #pragma unroll
            for (int nt = 0; nt < 2; ++nt) {
                f32x16 c;
                #pragma unroll
                for (int r = 0; r < 16; ++r) c[r] = 0.f;
                #pragma unroll
                for (int kk = 0; kk < 4; ++kk) c = MFMA32(a1f[kk], an[nt][kk], c);
                // C[m=f][n=i]: col=l31 -> i, row=(reg&3)+8*(reg>>2)+4*lh -> f
                const int i = nt * 32 + l31;
                #pragma unroll
                for (int g = 0; g < 4; ++g) {
                    const int f0 = g * 8 + 4 * lh;
                    bfv4 pv;
                    pv[0] = (__bf16)c[g * 4 + 0]; pv[1] = (__bf16)c[g * 4 + 1];
                    pv[2] = (__bf16)c[g * 4 + 2]; pv[3] = (__bf16)c[g * 4 + 3];
                    *(bfv4*)&catg[sl][i][f0] = pv;
                }
            }
        }

        // ---- Phase 2: GEMM2 (same-wave catg slices; compiler orders ds ops) ----
        #pragma unroll
        for (int p = 0; p < 4; ++p) {
            const int sp = p >> 1;
            const int sl = 2 * w + sp;
            const int ih = p & 1;
            const int i  = ih * 32 + l31;
            const float xv = sp ? (ih ? xv11 : xv10) : (ih ? xv01 : xv00);
            f32x16 c;
            #pragma unroll
            for (int r = 0; r < 16; ++r) c[r] = 0.f;
            #pragma unroll
            for (int kk = 0; kk < 2; ++kk) {   // h part, k in [0,32)
                bfv8 v;
                #pragma unroll
                for (int e = 0; e < 8; ++e)
                    v[e] = (__bf16)fmaxf(xv * w1k[kk][e] + b1k[kk][e], 0.f);
                c = MFMA32(v, wf[kk], c);
            }
            #pragma unroll
            for (int kk = 2; kk < 4; ++kk) {   // agg part, k in [32,64)
                const int f0 = (kk - 2) * 16 + lh * 8;
                const bfv4 lo = *(const bfv4*)&catg[sl][i][f0];
                const bfv4 hi = *(const bfv4*)&catg[sl][i][f0 + 4];
                bfv8 v;
                #pragma unroll
                for (int e = 0; e < 4; ++e) { v[e] = lo[e]; v[e + 4] = hi[e]; }
                c = MFMA32(v, wf[kk], c);
            }
            #pragma unroll
            for (int r = 0; r < 16; ++r) {
                const float h2 = fmaxf(c[r] + b2f, 0.f);
                if (ih == 0) macc0[r] += h2; else macc1[r] += h2;
            }
        }
    }

    // ---- epilogue: cross-wave reduce in LDS, then global atomics ----
    __syncthreads();   // red zeroing (top) visible to all waves before atomics
    #pragma unroll
    for (int r = 0; r < 16; ++r) {
        const int row = (r & 3) + 8 * (r >> 2) + 4 * lh;  // i within half
        atomicAdd(&red[row * HD + l31], macc0[r]);
        atomicAdd(&red[(row + 32) * HD + l31], macc1[r]);
    }
    __syncthreads();
    const float inv = 1.f / (float)SN;
    #pragma unroll
    for (int q = 0; q < (NV * HD) / 256; ++q) {
        const int e = tid + q * 256;       // e = i*HD + f
        atomicAdd(out + (size_t)b * (NV * HD) + e, red[e] * inv);
    }
}

extern "C" void kernel_launch(void* const* d_in, const int* in_sizes, int n_in,
                              void* d_out, int out_size, void* d_ws, size_t ws_size,
                              hipStream_t stream) {
    const float* x   = (const float*)d_in[0];
    const float* adj = (const float*)d_in[1];
    const float* w1  = (const float*)d_in[2];
    const float* b1  = (const float*)d_in[3];
    const float* w2  = (const float*)d_in[4];
    const float* b2  = (const float*)d_in[5];
    float* out = (float*)d_out;

    hipMemsetAsync(out, 0, (size_t)out_size * sizeof(float), stream);
    gnn_mfma<<<dim3(BN * 32), dim3(256), 0, stream>>>(x, adj, w1, b1, w2, b2, out);
}